// Round 14
// baseline (191.233 us; speedup 1.0000x reference)
//
#include <hip/hip_runtime.h>
#include <stdint.h>

#pragma clang fp contract(off)

#define BATCH 8
#define NANCH 200000
#define NGT   20
#define APT   9
#define CHUNK (256*APT)     // 2304
#define PB    96            // chunks per batch; 96*2304 = 221184 >= 200000
#define GRID  (PB*BATCH)    // 768 = exactly 3 blocks/CU on 256 CUs
#define HBITS 14
#define HBINS (1<<HBITS)    // 16384
#define HWORDS (2*BATCH*HBINS)  // 262144
#define HALF_FLAT 800000u   // (BATCH*NANCH)/2 threefry split

// ---- compile-time threefry for the two split keys ----
constexpr void ctf_round(uint32_t& x0, uint32_t& x1, int r) {
  x0 += x1; x1 = (x1 << r) | (x1 >> (32 - r)); x1 ^= x0;
}
constexpr uint64_t cenc(uint32_t k0, uint32_t k1, uint32_t x0, uint32_t x1) {
  uint32_t k2 = k0 ^ k1 ^ 0x1BD11BDAu;
  x0 += k0; x1 += k1;
  ctf_round(x0,x1,13); ctf_round(x0,x1,15); ctf_round(x0,x1,26); ctf_round(x0,x1,6);
  x0 += k1; x1 += k2 + 1u;
  ctf_round(x0,x1,17); ctf_round(x0,x1,29); ctf_round(x0,x1,16); ctf_round(x0,x1,24);
  x0 += k2; x1 += k0 + 2u;
  ctf_round(x0,x1,13); ctf_round(x0,x1,15); ctf_round(x0,x1,26); ctf_round(x0,x1,6);
  x0 += k0; x1 += k1 + 3u;
  ctf_round(x0,x1,17); ctf_round(x0,x1,29); ctf_round(x0,x1,16); ctf_round(x0,x1,24);
  x0 += k1; x1 += k2 + 4u;
  ctf_round(x0,x1,13); ctf_round(x0,x1,15); ctf_round(x0,x1,26); ctf_round(x0,x1,6);
  x0 += k2; x1 += k0 + 5u;
  return ((uint64_t)x1 << 32) | x0;
}
constexpr uint64_t EA = cenc(0u,42u,0u,2u);
constexpr uint64_t EB = cenc(0u,42u,1u,3u);
#define KF0 ((uint32_t)(EA & 0xFFFFFFFFu))
#define KF1 ((uint32_t)(EB & 0xFFFFFFFFu))
#define KG0 ((uint32_t)(EA >> 32))
#define KG1 ((uint32_t)(EB >> 32))

// ---- runtime threefry ----
__device__ __forceinline__ void tf_round(uint32_t& x0, uint32_t& x1, int r) {
  x0 += x1; x1 = (x1 << r) | (x1 >> (32 - r)); x1 ^= x0;
}
__device__ __forceinline__ void threefry2x32(uint32_t k0, uint32_t k1,
                                             uint32_t x0, uint32_t x1,
                                             uint32_t& o0, uint32_t& o1) {
  uint32_t k2 = k0 ^ k1 ^ 0x1BD11BDAu;
  x0 += k0; x1 += k1;
  tf_round(x0,x1,13); tf_round(x0,x1,15); tf_round(x0,x1,26); tf_round(x0,x1,6);
  x0 += k1; x1 += k2 + 1u;
  tf_round(x0,x1,17); tf_round(x0,x1,29); tf_round(x0,x1,16); tf_round(x0,x1,24);
  x0 += k2; x1 += k0 + 2u;
  tf_round(x0,x1,13); tf_round(x0,x1,15); tf_round(x0,x1,26); tf_round(x0,x1,6);
  x0 += k0; x1 += k1 + 3u;
  tf_round(x0,x1,17); tf_round(x0,x1,29); tf_round(x0,x1,16); tf_round(x0,x1,24);
  x0 += k1; x1 += k2 + 4u;
  tf_round(x0,x1,13); tf_round(x0,x1,15); tf_round(x0,x1,26); tf_round(x0,x1,6);
  x0 += k2; x1 += k0 + 5u;
  o0 = x0; o1 = x1;
}
__device__ __forceinline__ uint32_t rbits23(uint32_t kk0, uint32_t kk1, uint32_t f) {
  uint32_t o0, o1;
  if (f < HALF_FLAT) { threefry2x32(kk0, kk1, f, f + HALF_FLAT, o0, o1); return o0 >> 9; }
  else               { threefry2x32(kk0, kk1, f - HALF_FLAT, f, o0, o1); return o1 >> 9; }
}

// ---- K1: single IoU pass; 768 uniform blocks; k-loop fully unrolled ----
__global__ __launch_bounds__(256, 3)
void k_main(const float* __restrict__ gt, const float* __restrict__ anc,
            float* __restrict__ wavemax, uint32_t* __restrict__ aux,
            float* __restrict__ out_matches, float* __restrict__ out_inds,
            float* __restrict__ out_anch, uint32_t* __restrict__ hist,
            int* __restrict__ gtmax_bits) {
  const int bid = blockIdx.x, t = threadIdx.x;
  const int b = bid / PB, blk = bid % PB;
  // zero hist for K2's atomics (196608 threads, <=2 words each)
  for (uint32_t i = (uint32_t)(bid*256 + t); i < HWORDS;
       i += (uint32_t)(GRID*256)) hist[i] = 0u;

  __shared__ float sx1[NGT], sy1[NGT], sx2p[NGT], sy2p[NGT], sar[NGT];
  __shared__ int   ssz[NGT];
  __shared__ int   smax[NGT];
  if (t < NGT) {
    const float* p = gt + (size_t)(b*NGT + t)*5;
    float x1=p[0], y1=p[1], x2=p[2], y2=p[3];
    float w = x2 - x1 + 1.0f, h = y2 - y1 + 1.0f;
    sx1[t]=x1; sy1[t]=y1; sx2p[t]=x2+1.0f; sy2p[t]=y2+1.0f; sar[t]=w*h;
    ssz[t] = (w==1.0f) && (h==1.0f);
    smax[t] = 0xBF800000;   // bits of -1.0f; all real wavemax >= 0.0f
  }
  __syncthreads();

  const float4* a4 = (const float4*)anc;
  const int base = blk*CHUNK + t;
  float4 av[APT]; float aarea[APT], ax2p[APT], ay2p[APT];
  bool anz[APT], valid[APT];
#pragma unroll
  for (int j=0;j<APT;j++) {
    int n = base + j*256;
    valid[j] = n < NANCH;
    if (n > NANCH-1) n = NANCH-1;   // clamped dup: max-neutral, outputs skipped
    av[j] = a4[n];
    float aw = av[j].z-av[j].x+1.0f, ah = av[j].w-av[j].y+1.0f;
    aarea[j] = aw*ah;
    anz[j] = (aw==1.0f)&&(ah==1.0f);
    ax2p[j] = av[j].z + 1.0f;
    ay2p[j] = av[j].w + 1.0f;
  }
  float best[APT]; int arg[APT]; uint32_t Mloc[APT]; float tm[NGT];
#pragma unroll
  for (int j=0;j<APT;j++) { best[j]=-3.0f; arg[j]=0; Mloc[j]=0u; }
  // ---- hot loop: FULLY UNROLLED — LDS offsets become immediates, compiler
  //      hoists/batches the broadcast reads and pipelines across k ----
#pragma unroll
  for (int k=0;k<NGT;k++) {
    float kx1=sx1[k], ky1=sy1[k], kx2p=sx2p[k], ky2p=sy2p[k], kar=sar[k];
    bool kz = ssz[k];
    float ovv[APT]; float tmk = -3.0f;
#pragma unroll
    for (int j=0;j<APT;j++) {
      float iw = fminf(ax2p[j], kx2p) - fmaxf(av[j].x, kx1);
      float ih = fminf(ay2p[j], ky2p) - fmaxf(av[j].y, ky1);
      float inter = fmaxf(iw,0.0f)*fmaxf(ih,0.0f);
      float ov = inter * __builtin_amdgcn_rcpf((aarea[j] + kar) - inter);
      if (kz)     ov = 0.0f;
      if (anz[j]) ov = -1.0f;
      ovv[j] = ov;
      if (ov > best[j]) { best[j] = ov; arg[j] = k; }  // first-occurrence argmax
      tmk = fmaxf(tmk, ov);
    }
#pragma unroll
    for (int j=0;j<APT;j++) if (ovv[j] == tmk) Mloc[j] |= (1u<<k);
    tm[k] = tmk;
  }
  // ---- post-loop: butterflies; per-lane wm; kmask = (tm[k]==wavemax_k) ----
  const int wid = bid*4 + (t>>6);
  const int lane = t & 63;
  uint32_t kmask = 0u; float wm = 0.0f;
#pragma unroll
  for (int k=0;k<NGT;k++) {
    float v = tm[k];
#pragma unroll
    for (int s=32;s>=1;s>>=1) v = fmaxf(v, __shfl_xor(v, s, 64));
    if (tm[k] == v) kmask |= (1u<<k);
    if (lane == k) wm = v;
  }
  if (lane < NGT) {
    wavemax[(size_t)wid*NGT + lane] = wm;             // one 80B wave store
    atomicMax(&smax[lane], __float_as_int(wm));       // block-level reduce
  }
  __syncthreads();
  if (t < NGT) atomicMax(&gtmax_bits[b*NGT + t], smax[t]);  // 20 atomics/block
  // ---- outputs independent of later phases ----
  float4* oa4 = (float4*)out_anch;
#pragma unroll
  for (int j=0;j<APT;j++) {
    int n = base + j*256;
    if (!valid[j]) continue;
    uint32_t a = ((Mloc[j] & kmask)<<2) |
                 ((best[j] >= 0.7f) ? 2u : 0u) | ((best[j] < 0.3f) ? 1u : 0u);
    aux[(size_t)b*NANCH + n] = a;
    out_matches[(size_t)b*NANCH + n] = (float)(arg[j] + b*NGT);
    if (b == 0) { out_inds[n] = (float)n; oa4[n] = av[j]; }
  }
}

// ---- K2: resolve keep, code, hash, histogram, combo ----
__global__ __launch_bounds__(256, 4)
void k_code(const uint32_t* __restrict__ aux, const float* __restrict__ wavemax,
            const int* __restrict__ gtmax_bits, uint32_t* __restrict__ combo,
            uint32_t* __restrict__ hist) {
  const int bid = blockIdx.x, t = threadIdx.x;
  const int b = bid / PB, blk = bid % PB;
  const int lane = t & 63;
  const int wid = bid*4 + (t>>6);
  bool cond = false;
  if (lane < NGT) {
    float gv = __int_as_float(gtmax_bits[b*NGT + lane]);
    float rep = (gv == 0.0f) ? 1e-5f : gv;            // ref's gt_max fixup
    cond = (wavemax[(size_t)wid*NGT + lane] == rep);  // ov==rep <=> M-bit && this
  }
  uint32_t wk = (uint32_t)__ballot(cond);
  const int base = blk*CHUNK + t;
#pragma unroll
  for (int j=0;j<APT;j++) {
    int n = base + j*256; if (n >= NANCH) break;
    uint32_t a = aux[(size_t)b*NANCH + n];
    uint32_t code = 0;
    if (a & 1u) code = 1;                    // best < 0.3
    if ((a>>2) & wk) code = 2;               // keep (achieves gt_max)
    if (a & 2u) code = 2;                    // best >= 0.7
    uint32_t f = (uint32_t)(b*NANCH + n);
    uint32_t rb = rbits23((code==2)?KF0:KG0, (code==2)?KF1:KG1, f);
    combo[(size_t)b*NANCH + n] = (code<<30) | rb;
    if (code) atomicAdd(&hist[b*2*HBINS + ((code==2)?0:HBINS) + (rb>>9)], 1u);
  }
}

// ---- K3: per-batch selection over 14-bit hist (fg then bg) ----
__global__ __launch_bounds__(256) void k_sel(const uint32_t* __restrict__ hist,
                                             uint32_t* __restrict__ thr) {
  const int b = blockIdx.x, t = threadIdx.x;
  __shared__ uint32_t ls[256];
  __shared__ uint32_t s_keptfg;
  for (int m = 0; m < 2; m++) {
    const uint32_t* h = hist + b*2*HBINS + m*HBINS;   // 64 bins/thread
    uint32_t s = 0;
    for (int i=0;i<64;i++) s += h[64*t+i];
    ls[t] = s; __syncthreads();
#pragma unroll
    for (int off=1; off<256; off<<=1) {
      uint32_t v = (t>=off) ? ls[t-off] : 0u; __syncthreads();
      ls[t] += v; __syncthreads();
    }
    uint32_t total = ls[255];
    uint32_t incl  = ls[t], excl = incl - s;
    uint32_t target = (m==0) ? 128u : (256u - s_keptfg);
    if (total <= target) {
      if (t == 0) thr[2*b+m] = HBINS-1;               // keep all
    } else if (excl < target && target <= incl) {     // unique owner
      uint32_t cum = excl, j = 64*t;
      for (int i=0;i<64;i++) {
        uint32_t c = h[64*t+i];
        if (cum + c >= target) { j = 64*t+i; break; }
        cum += c;
      }
      thr[2*b+m] = j;                                  // keep rb14 <= j
    }
    if (m == 0 && t == 0) s_keptfg = (total < 128u) ? total : 128u;
    __syncthreads();
  }
}

// ---- K4: final labels ----
__global__ __launch_bounds__(256) void k_final(const uint32_t* __restrict__ combo,
                                               const uint32_t* __restrict__ thr,
                                               float* __restrict__ out_labels) {
  const int bid = blockIdx.x, t = threadIdx.x;
  const int b = bid / PB, blk = bid % PB;
  uint32_t rF = thr[2*b], rB = thr[2*b+1];
  const int base = blk*CHUNK + t;
#pragma unroll
  for (int j=0;j<APT;j++) {
    int n = base + j*256; if (n >= NANCH) break;
    uint32_t u = combo[(size_t)b*NANCH + n];
    uint32_t lab = u >> 30, rb14 = (u & 0x7FFFFFu) >> 9;
    float o = -1.0f;
    if (lab == 1)      o = (rb14 <= rB) ? 0.0f : -1.0f;
    else if (lab == 2) o = (rb14 <= rF) ? 1.0f : -1.0f;
    out_labels[(size_t)b*NANCH + n] = o;
  }
}

extern "C" void kernel_launch(void* const* d_in, const int* in_sizes, int n_in,
                              void* d_out, int out_size, void* d_ws, size_t ws_size,
                              hipStream_t stream) {
  const float* gt  = (const float*)d_in[1];   // gt_boxes (8,20,5) f32
  const float* anc = (const float*)d_in[4];   // anchors (1,200000,4) f32

  float* out         = (float*)d_out;
  float* out_labels  = out;                                  // [0, 1.6M)
  float* out_matches = out + (size_t)BATCH*NANCH;            // [1.6M, 3.2M)
  float* out_inds    = out + (size_t)2*BATCH*NANCH;          // [3.2M, 3.4M)
  float* out_anch    = out_inds + NANCH;                     // [3.4M, 4.2M)

  char* ws = (char*)d_ws;
  int*      gtmax   = (int*)(ws + 0);             // 160 words; 0xAA poison is a
                                                  // valid atomicMax identity
  uint32_t* hist    = (uint32_t*)(ws + 1024);     // 1 MB (zeroed in k_main)
  uint32_t* thr     = (uint32_t*)(ws + 1049600);  // 64 B (pad 1KB)
  float*    wavemax = (float*)(ws + 1050624);     // 3072 waves * 20 * 4 = 245,760
  uint32_t* aux     = (uint32_t*)(ws + 1298432);  // 6.4 MB
  uint32_t* combo   = (uint32_t*)(ws + 7698432);  // 6.4 MB

  k_main <<<GRID, 256, 0, stream>>>(gt, anc, wavemax, aux, out_matches,
                                    out_inds, out_anch, hist, gtmax);
  k_code <<<GRID, 256, 0, stream>>>(aux, wavemax, gtmax, combo, hist);
  k_sel  <<<BATCH, 256, 0, stream>>>(hist, thr);
  k_final<<<GRID, 256, 0, stream>>>(combo, thr, out_labels);
}

// Round 15
// 158.322 us; speedup vs baseline: 1.2079x; 1.2079x over previous
//
#include <hip/hip_runtime.h>
#include <stdint.h>

#pragma clang fp contract(off)

#define BATCH 8
#define NANCH 200000
#define NGT   20
#define APT   9
#define CHUNK (256*APT)     // 2304
#define PB    96            // chunks per batch; 96*2304 = 221184 >= 200000
#define GRID  (PB*BATCH)    // 768 = exactly 3 blocks/CU on 256 CUs
#define HBITS 14
#define HBINS (1<<HBITS)    // 16384
#define HWORDS (2*BATCH*HBINS)  // 262144
#define HALF_FLAT 800000u   // (BATCH*NANCH)/2 threefry split

// ---- compile-time threefry for the two split keys ----
constexpr void ctf_round(uint32_t& x0, uint32_t& x1, int r) {
  x0 += x1; x1 = (x1 << r) | (x1 >> (32 - r)); x1 ^= x0;
}
constexpr uint64_t cenc(uint32_t k0, uint32_t k1, uint32_t x0, uint32_t x1) {
  uint32_t k2 = k0 ^ k1 ^ 0x1BD11BDAu;
  x0 += k0; x1 += k1;
  ctf_round(x0,x1,13); ctf_round(x0,x1,15); ctf_round(x0,x1,26); ctf_round(x0,x1,6);
  x0 += k1; x1 += k2 + 1u;
  ctf_round(x0,x1,17); ctf_round(x0,x1,29); ctf_round(x0,x1,16); ctf_round(x0,x1,24);
  x0 += k2; x1 += k0 + 2u;
  ctf_round(x0,x1,13); ctf_round(x0,x1,15); ctf_round(x0,x1,26); ctf_round(x0,x1,6);
  x0 += k0; x1 += k1 + 3u;
  ctf_round(x0,x1,17); ctf_round(x0,x1,29); ctf_round(x0,x1,16); ctf_round(x0,x1,24);
  x0 += k1; x1 += k2 + 4u;
  ctf_round(x0,x1,13); ctf_round(x0,x1,15); ctf_round(x0,x1,26); ctf_round(x0,x1,6);
  x0 += k2; x1 += k0 + 5u;
  return ((uint64_t)x1 << 32) | x0;
}
constexpr uint64_t EA = cenc(0u,42u,0u,2u);
constexpr uint64_t EB = cenc(0u,42u,1u,3u);
#define KF0 ((uint32_t)(EA & 0xFFFFFFFFu))
#define KF1 ((uint32_t)(EB & 0xFFFFFFFFu))
#define KG0 ((uint32_t)(EA >> 32))
#define KG1 ((uint32_t)(EB >> 32))

// ---- runtime threefry ----
__device__ __forceinline__ void tf_round(uint32_t& x0, uint32_t& x1, int r) {
  x0 += x1; x1 = (x1 << r) | (x1 >> (32 - r)); x1 ^= x0;
}
__device__ __forceinline__ void threefry2x32(uint32_t k0, uint32_t k1,
                                             uint32_t x0, uint32_t x1,
                                             uint32_t& o0, uint32_t& o1) {
  uint32_t k2 = k0 ^ k1 ^ 0x1BD11BDAu;
  x0 += k0; x1 += k1;
  tf_round(x0,x1,13); tf_round(x0,x1,15); tf_round(x0,x1,26); tf_round(x0,x1,6);
  x0 += k1; x1 += k2 + 1u;
  tf_round(x0,x1,17); tf_round(x0,x1,29); tf_round(x0,x1,16); tf_round(x0,x1,24);
  x0 += k2; x1 += k0 + 2u;
  tf_round(x0,x1,13); tf_round(x0,x1,15); tf_round(x0,x1,26); tf_round(x0,x1,6);
  x0 += k0; x1 += k1 + 3u;
  tf_round(x0,x1,17); tf_round(x0,x1,29); tf_round(x0,x1,16); tf_round(x0,x1,24);
  x0 += k1; x1 += k2 + 4u;
  tf_round(x0,x1,13); tf_round(x0,x1,15); tf_round(x0,x1,26); tf_round(x0,x1,6);
  x0 += k2; x1 += k0 + 5u;
  o0 = x0; o1 = x1;
}
__device__ __forceinline__ uint32_t rbits23(uint32_t kk0, uint32_t kk1, uint32_t f) {
  uint32_t o0, o1;
  if (f < HALF_FLAT) { threefry2x32(kk0, kk1, f, f + HALF_FLAT, o0, o1); return o0 >> 9; }
  else               { threefry2x32(kk0, kk1, f - HALF_FLAT, f, o0, o1); return o1 >> 9; }
}

// ---- K1: single IoU pass; 768 uniform blocks; ROLLED k-loop (unroll spills) ----
__global__ __launch_bounds__(256, 3)
void k_main(const float* __restrict__ gt, const float* __restrict__ anc,
            float* __restrict__ wavemax, uint32_t* __restrict__ aux,
            float* __restrict__ out_matches, float* __restrict__ out_inds,
            float* __restrict__ out_anch, uint32_t* __restrict__ hist,
            int* __restrict__ gtmax_bits) {
  const int bid = blockIdx.x, t = threadIdx.x;
  const int b = bid / PB, blk = bid % PB;
  // zero hist for K2's atomics (196608 threads, <=2 words each)
  for (uint32_t i = (uint32_t)(bid*256 + t); i < HWORDS;
       i += (uint32_t)(GRID*256)) hist[i] = 0u;

  __shared__ float sx1[NGT], sy1[NGT], sx2p[NGT], sy2p[NGT], sar[NGT];
  __shared__ int   ssz[NGT];
  __shared__ int   smax[NGT];
  if (t < NGT) {
    const float* p = gt + (size_t)(b*NGT + t)*5;
    float x1=p[0], y1=p[1], x2=p[2], y2=p[3];
    float w = x2 - x1 + 1.0f, h = y2 - y1 + 1.0f;
    sx1[t]=x1; sy1[t]=y1; sx2p[t]=x2+1.0f; sy2p[t]=y2+1.0f; sar[t]=w*h;
    ssz[t] = (w==1.0f) && (h==1.0f);
    smax[t] = 0xBF800000;   // bits of -1.0f; all real wavemax >= 0.0f
  }
  __syncthreads();

  const float4* a4 = (const float4*)anc;
  const int base = blk*CHUNK + t;
  float4 av[APT]; float aarea[APT], ax2p[APT], ay2p[APT];
  bool anz[APT], valid[APT];
#pragma unroll
  for (int j=0;j<APT;j++) {
    int n = base + j*256;
    valid[j] = n < NANCH;
    if (n > NANCH-1) n = NANCH-1;   // clamped dup: max-neutral, outputs skipped
    av[j] = a4[n];
    float aw = av[j].z-av[j].x+1.0f, ah = av[j].w-av[j].y+1.0f;
    aarea[j] = aw*ah;
    anz[j] = (aw==1.0f)&&(ah==1.0f);
    ax2p[j] = av[j].z + 1.0f;
    ay2p[j] = av[j].w + 1.0f;
  }
  float best[APT]; int arg[APT]; uint32_t Mloc[APT]; float tm[NGT];
#pragma unroll
  for (int j=0;j<APT;j++) { best[j]=-3.0f; arg[j]=0; Mloc[j]=0u; }
  // ---- hot loop: rolled over k (full unroll spills to scratch — r14) ----
  for (int k=0;k<NGT;k++) {
    float kx1=sx1[k], ky1=sy1[k], kx2p=sx2p[k], ky2p=sy2p[k], kar=sar[k];
    bool kz = ssz[k];
    float ovv[APT]; float tmk = -3.0f;
#pragma unroll
    for (int j=0;j<APT;j++) {
      float iw = fminf(ax2p[j], kx2p) - fmaxf(av[j].x, kx1);
      float ih = fminf(ay2p[j], ky2p) - fmaxf(av[j].y, ky1);
      float inter = fmaxf(iw,0.0f)*fmaxf(ih,0.0f);
      float ov = inter * __builtin_amdgcn_rcpf((aarea[j] + kar) - inter);
      if (kz)     ov = 0.0f;
      if (anz[j]) ov = -1.0f;
      ovv[j] = ov;
      if (ov > best[j]) { best[j] = ov; arg[j] = k; }  // first-occurrence argmax
      tmk = fmaxf(tmk, ov);
    }
#pragma unroll
    for (int j=0;j<APT;j++) if (ovv[j] == tmk) Mloc[j] |= (1u<<k);
    tm[k] = tmk;
  }
  // ---- post-loop: butterflies; per-lane wm; kmask = (tm[k]==wavemax_k) ----
  const int wid = bid*4 + (t>>6);
  const int lane = t & 63;
  uint32_t kmask = 0u; float wm = 0.0f;
#pragma unroll
  for (int k=0;k<NGT;k++) {
    float v = tm[k];
#pragma unroll
    for (int s=32;s>=1;s>>=1) v = fmaxf(v, __shfl_xor(v, s, 64));
    if (tm[k] == v) kmask |= (1u<<k);
    if (lane == k) wm = v;
  }
  if (lane < NGT) {
    wavemax[(size_t)wid*NGT + lane] = wm;             // one 80B wave store
    atomicMax(&smax[lane], __float_as_int(wm));       // block-level reduce
  }
  __syncthreads();
  if (t < NGT) atomicMax(&gtmax_bits[b*NGT + t], smax[t]);  // 20 atomics/block
  // ---- outputs independent of later phases ----
  float4* oa4 = (float4*)out_anch;
#pragma unroll
  for (int j=0;j<APT;j++) {
    int n = base + j*256;
    if (!valid[j]) continue;
    uint32_t a = ((Mloc[j] & kmask)<<2) |
                 ((best[j] >= 0.7f) ? 2u : 0u) | ((best[j] < 0.3f) ? 1u : 0u);
    aux[(size_t)b*NANCH + n] = a;
    out_matches[(size_t)b*NANCH + n] = (float)(arg[j] + b*NGT);
    if (b == 0) { out_inds[n] = (float)n; oa4[n] = av[j]; }
  }
}

// ---- K2: resolve keep, code, hash, histogram, combo ----
__global__ __launch_bounds__(256, 4)
void k_code(const uint32_t* __restrict__ aux, const float* __restrict__ wavemax,
            const int* __restrict__ gtmax_bits, uint32_t* __restrict__ combo,
            uint32_t* __restrict__ hist) {
  const int bid = blockIdx.x, t = threadIdx.x;
  const int b = bid / PB, blk = bid % PB;
  const int lane = t & 63;
  const int wid = bid*4 + (t>>6);
  bool cond = false;
  if (lane < NGT) {
    float gv = __int_as_float(gtmax_bits[b*NGT + lane]);
    float rep = (gv == 0.0f) ? 1e-5f : gv;            // ref's gt_max fixup
    cond = (wavemax[(size_t)wid*NGT + lane] == rep);  // ov==rep <=> M-bit && this
  }
  uint32_t wk = (uint32_t)__ballot(cond);
  const int base = blk*CHUNK + t;
#pragma unroll
  for (int j=0;j<APT;j++) {
    int n = base + j*256; if (n >= NANCH) break;
    uint32_t a = aux[(size_t)b*NANCH + n];
    uint32_t code = 0;
    if (a & 1u) code = 1;                    // best < 0.3
    if ((a>>2) & wk) code = 2;               // keep (achieves gt_max)
    if (a & 2u) code = 2;                    // best >= 0.7
    uint32_t f = (uint32_t)(b*NANCH + n);
    uint32_t rb = rbits23((code==2)?KF0:KG0, (code==2)?KF1:KG1, f);
    combo[(size_t)b*NANCH + n] = (code<<30) | rb;
    if (code) atomicAdd(&hist[b*2*HBINS + ((code==2)?0:HBINS) + (rb>>9)], 1u);
  }
}

// ---- K3: per-batch selection over 14-bit hist (fg then bg) ----
__global__ __launch_bounds__(256) void k_sel(const uint32_t* __restrict__ hist,
                                             uint32_t* __restrict__ thr) {
  const int b = blockIdx.x, t = threadIdx.x;
  __shared__ uint32_t ls[256];
  __shared__ uint32_t s_keptfg;
  for (int m = 0; m < 2; m++) {
    const uint32_t* h = hist + b*2*HBINS + m*HBINS;   // 64 bins/thread
    uint32_t s = 0;
    for (int i=0;i<64;i++) s += h[64*t+i];
    ls[t] = s; __syncthreads();
#pragma unroll
    for (int off=1; off<256; off<<=1) {
      uint32_t v = (t>=off) ? ls[t-off] : 0u; __syncthreads();
      ls[t] += v; __syncthreads();
    }
    uint32_t total = ls[255];
    uint32_t incl  = ls[t], excl = incl - s;
    uint32_t target = (m==0) ? 128u : (256u - s_keptfg);
    if (total <= target) {
      if (t == 0) thr[2*b+m] = HBINS-1;               // keep all
    } else if (excl < target && target <= incl) {     // unique owner
      uint32_t cum = excl, j = 64*t;
      for (int i=0;i<64;i++) {
        uint32_t c = h[64*t+i];
        if (cum + c >= target) { j = 64*t+i; break; }
        cum += c;
      }
      thr[2*b+m] = j;                                  // keep rb14 <= j
    }
    if (m == 0 && t == 0) s_keptfg = (total < 128u) ? total : 128u;
    __syncthreads();
  }
}

// ---- K4: final labels ----
__global__ __launch_bounds__(256) void k_final(const uint32_t* __restrict__ combo,
                                               const uint32_t* __restrict__ thr,
                                               float* __restrict__ out_labels) {
  const int bid = blockIdx.x, t = threadIdx.x;
  const int b = bid / PB, blk = bid % PB;
  uint32_t rF = thr[2*b], rB = thr[2*b+1];
  const int base = blk*CHUNK + t;
#pragma unroll
  for (int j=0;j<APT;j++) {
    int n = base + j*256; if (n >= NANCH) break;
    uint32_t u = combo[(size_t)b*NANCH + n];
    uint32_t lab = u >> 30, rb14 = (u & 0x7FFFFFu) >> 9;
    float o = -1.0f;
    if (lab == 1)      o = (rb14 <= rB) ? 0.0f : -1.0f;
    else if (lab == 2) o = (rb14 <= rF) ? 1.0f : -1.0f;
    out_labels[(size_t)b*NANCH + n] = o;
  }
}

extern "C" void kernel_launch(void* const* d_in, const int* in_sizes, int n_in,
                              void* d_out, int out_size, void* d_ws, size_t ws_size,
                              hipStream_t stream) {
  const float* gt  = (const float*)d_in[1];   // gt_boxes (8,20,5) f32
  const float* anc = (const float*)d_in[4];   // anchors (1,200000,4) f32

  float* out         = (float*)d_out;
  float* out_labels  = out;                                  // [0, 1.6M)
  float* out_matches = out + (size_t)BATCH*NANCH;            // [1.6M, 3.2M)
  float* out_inds    = out + (size_t)2*BATCH*NANCH;          // [3.2M, 3.4M)
  float* out_anch    = out_inds + NANCH;                     // [3.4M, 4.2M)

  char* ws = (char*)d_ws;
  int*      gtmax   = (int*)(ws + 0);             // 160 words; 0xAA poison is a
                                                  // valid atomicMax identity
  uint32_t* hist    = (uint32_t*)(ws + 1024);     // 1 MB (zeroed in k_main)
  uint32_t* thr     = (uint32_t*)(ws + 1049600);  // 64 B (pad 1KB)
  float*    wavemax = (float*)(ws + 1050624);     // 3072 waves * 20 * 4 = 245,760
  uint32_t* aux     = (uint32_t*)(ws + 1298432);  // 6.4 MB
  uint32_t* combo   = (uint32_t*)(ws + 7698432);  // 6.4 MB

  k_main <<<GRID, 256, 0, stream>>>(gt, anc, wavemax, aux, out_matches,
                                    out_inds, out_anch, hist, gtmax);
  k_code <<<GRID, 256, 0, stream>>>(aux, wavemax, gtmax, combo, hist);
  k_sel  <<<BATCH, 256, 0, stream>>>(hist, thr);
  k_final<<<GRID, 256, 0, stream>>>(combo, thr, out_labels);
}